// Round 11
// baseline (172.246 us; speedup 1.0000x reference)
//
#include <hip/hip_runtime.h>

#define DEVI __device__ __forceinline__

typedef __bf16 bf16x8 __attribute__((ext_vector_type(8)));
typedef float f32x4 __attribute__((ext_vector_type(4)));

// B=4, C=256, H=W=48 -> N=2304, heads=8, hd=32
// fold 1/sqrt(32) * log2(e) into q so MFMA scores are already in exp2 domain
#define QSCALE 0.25503488f

#if __has_builtin(__builtin_amdgcn_exp2f)
#define EXP2(x) __builtin_amdgcn_exp2f(x)
#else
#define EXP2(x) __expf(0.69314718055994531f * (x))
#endif

DEVI unsigned short bfbits(float f) {
  union { __bf16 h; unsigned short u; } x;
  x.h = (__bf16)f;
  return x.u;
}
DEVI unsigned packbf2(float a, float b) {
  return (unsigned)bfbits(a) | ((unsigned)bfbits(b) << 16);
}
DEVI float bflo(unsigned u) { return __uint_as_float(u << 16); }
DEVI float bfhi(unsigned u) { return __uint_as_float(u & 0xffff0000u); }

DEVI void gload16(const unsigned short* g, void* l) {
  __builtin_amdgcn_global_load_lds((__attribute__((address_space(1))) const unsigned*)g,
                                   (__attribute__((address_space(3))) unsigned*)l, 16, 0, 0);
}

// ---------- K_A: fused QKV projection + Wo convert ----------
// grid (160): blocks 0..143 = (b = bid/36, n-block of 64 pixels); 144..159 = Wo cvt.
// Phase 1: x[b,:,n0..n0+64) f32 -> xtile[64 n][256 c] bf16, XOR-swizzled, via
//          in-LDS 64x65 f32 transpose (no global xT intermediate).
// Phase 2: per o-chunk of 64: stage Wq+Wk chunks f32->bf16 swizzled; each wave
//          computes D[n=16][o=64] for both mats from register-resident A-frags.
//          q scaled by QSCALE. Output head-major qhm/khm [b*8+h][2304][32].
// Phase 3: per o-chunk: stage Wv; D[o][n] -> vN [b][c][2304].
__global__ __launch_bounds__(256) void k_qkv(const float* __restrict__ x,
                                             const float* __restrict__ Wq,
                                             const float* __restrict__ Wk,
                                             const float* __restrict__ Wv,
                                             const float* __restrict__ Wo,
                                             unsigned short* __restrict__ qhm,
                                             unsigned short* __restrict__ khm,
                                             unsigned short* __restrict__ vN,
                                             unsigned short* __restrict__ WoB) {
  const int bid = blockIdx.x;
  const int t = threadIdx.x;
  if (bid >= 144) {  // Wo f32 -> bf16 (16 blocks x 256 thr x 16 elems)
    const int i = ((bid - 144) * 256 + t) * 16;
#pragma unroll
    for (int j = 0; j < 4; ++j) {
      const float4 v = *(const float4*)(Wo + i + j * 4);
      uint2 u;
      u.x = packbf2(v.x, v.y);
      u.y = packbf2(v.z, v.w);
      *(uint2*)(WoB + i + j * 4) = u;
    }
    return;
  }
  __shared__ __align__(16) unsigned char xtile[32768];
  __shared__ __align__(16) unsigned char wtile[32768];
  __shared__ __align__(16) unsigned char wtile2[32768];
  const int b = bid / 36, n0 = (bid % 36) * 64;
  const int l = t & 63, w = t >> 6;
  const int lr = l & 15, lg = l >> 4;
  const int tn = t & 63, tg = t >> 6;

  // ---- Phase 1: x -> xtile (bf16, transposed, swizzled) ----
  float* tmp = (float*)wtile;  // 64x65 f32 scratch (16.6 KB)
  for (int cb = 0; cb < 4; ++cb) {
    const float* xp = x + ((size_t)b * 256 + cb * 64) * 2304 + n0;
#pragma unroll
    for (int i = 0; i < 16; ++i) {
      const int c = tg * 16 + i;
      tmp[c * 65 + tn] = xp[(size_t)c * 2304 + tn];
    }
    __syncthreads();
    {
      unsigned u[8];
#pragma unroll
      for (int j = 0; j < 8; ++j)
        u[j] = packbf2(tmp[(tg * 16 + 2 * j) * 65 + tn], tmp[(tg * 16 + 2 * j + 1) * 65 + tn]);
      unsigned char* dst = xtile + tn * 512;
      const unsigned base = (unsigned)(cb * 128 + tg * 32);
      const unsigned swz = (unsigned)((tn & 7) << 4);
      *(uint4*)(dst + (base ^ swz)) = *(uint4*)&u[0];
      *(uint4*)(dst + ((base + 16) ^ swz)) = *(uint4*)&u[4];
    }
    __syncthreads();
  }

  // A-fragments (x rows w*16+lr), register-resident for all of phase 2
  bf16x8 a[8];
#pragma unroll
  for (int ks = 0; ks < 8; ++ks)
    a[ks] = *(const bf16x8*)(xtile + (w * 16 + lr) * 512 +
                             (((unsigned)((ks * 4 + lg) * 16)) ^ ((lr & 7) << 4)));

  // ---- Phase 2: q and k ----
  for (int oc = 0; oc < 4; ++oc) {
    {  // stage Wq chunk -> wtile, Wk chunk -> wtile2 (128 threads each)
      const int mat = t >> 7;
      const int t2 = t & 127;
      const int row = t2 >> 1;         // 0..63
      const int cj0 = (t2 & 1) * 16;   // 16 chunks of 16B
      const float* wp = (mat ? Wk : Wq) + (size_t)(oc * 64 + row) * 256;
      unsigned char* ldst = (mat ? wtile2 : wtile) + row * 512;
      const unsigned swz = (unsigned)((row & 7) << 4);
#pragma unroll
      for (int i = 0; i < 16; ++i) {
        const int cj = cj0 + i;
        const float4 v0 = *(const float4*)(wp + cj * 8);
        const float4 v1 = *(const float4*)(wp + cj * 8 + 4);
        uint4 u;
        u.x = packbf2(v0.x, v0.y);
        u.y = packbf2(v0.z, v0.w);
        u.z = packbf2(v1.x, v1.y);
        u.w = packbf2(v1.z, v1.w);
        *(uint4*)(ldst + (((unsigned)(cj * 16)) ^ swz)) = u;
      }
    }
    __syncthreads();
#pragma unroll
    for (int m = 0; m < 2; ++m) {
      const unsigned char* wsrc = m ? wtile2 : wtile;
      unsigned short* outp = m ? khm : qhm;
      const float scale = m ? 1.0f : QSCALE;
      f32x4 acc[4];
#pragma unroll
      for (int ot = 0; ot < 4; ++ot) acc[ot] = (f32x4){0.f, 0.f, 0.f, 0.f};
      for (int ks = 0; ks < 8; ++ks) {
#pragma unroll
        for (int ot = 0; ot < 4; ++ot) {
          const int brow = ot * 16 + lr;
          const bf16x8 bfr = *(const bf16x8*)(wsrc + brow * 512 +
                                              (((unsigned)((ks * 4 + lg) * 16)) ^ ((brow & 7) << 4)));
          acc[ot] = __builtin_amdgcn_mfma_f32_16x16x32_bf16(a[ks], bfr, acc[ot], 0, 0, 0);
        }
      }
#pragma unroll
      for (int ot = 0; ot < 4; ++ot) {
        const int h = 2 * oc + (ot >> 1);
        const int d = (ot & 1) * 16 + lr;
        const size_t slab = (size_t)(b * 8 + h) * 2304;
#pragma unroll
        for (int r = 0; r < 4; ++r) {
          const int n = n0 + w * 16 + lg * 4 + r;
          outp[(slab + n) * 32 + d] = bfbits(acc[ot][r] * scale);
        }
      }
    }
    __syncthreads();
  }

  // ---- Phase 3: v ----
  for (int oc = 0; oc < 4; ++oc) {
    {  // stage Wv chunk -> wtile
      const int row = t >> 2;        // 0..63
      const int cj0 = (t & 3) * 8;   // 8 chunks of 16B
      const float* wp = Wv + (size_t)(oc * 64 + row) * 256;
      unsigned char* ldst = wtile + row * 512;
      const unsigned swz = (unsigned)((row & 7) << 4);
#pragma unroll
      for (int i = 0; i < 8; ++i) {
        const int cj = cj0 + i;
        const float4 v0 = *(const float4*)(wp + cj * 8);
        const float4 v1 = *(const float4*)(wp + cj * 8 + 4);
        uint4 u;
        u.x = packbf2(v0.x, v0.y);
        u.y = packbf2(v0.z, v0.w);
        u.z = packbf2(v1.x, v1.y);
        u.w = packbf2(v1.z, v1.w);
        *(uint4*)(ldst + (((unsigned)(cj * 16)) ^ swz)) = u;
      }
    }
    __syncthreads();
    f32x4 acc[4];
#pragma unroll
    for (int nt = 0; nt < 4; ++nt) acc[nt] = (f32x4){0.f, 0.f, 0.f, 0.f};
    for (int ks = 0; ks < 8; ++ks) {
      const int arow = w * 16 + lr;
      const bf16x8 aw = *(const bf16x8*)(wtile + arow * 512 +
                                         (((unsigned)((ks * 4 + lg) * 16)) ^ ((arow & 7) << 4)));
#pragma unroll
      for (int nt = 0; nt < 4; ++nt) {
        const int brow = nt * 16 + lr;
        const bf16x8 bx = *(const bf16x8*)(xtile + brow * 512 +
                                           (((unsigned)((ks * 4 + lg) * 16)) ^ ((brow & 7) << 4)));
        acc[nt] = __builtin_amdgcn_mfma_f32_16x16x32_bf16(aw, bx, acc[nt], 0, 0, 0);
      }
    }
#pragma unroll
    for (int nt = 0; nt < 4; ++nt)
#pragma unroll
      for (int r = 0; r < 4; ++r) {
        const int o = oc * 64 + w * 16 + lg * 4 + r;
        const int n = n0 + nt * 16 + lr;
        vN[(size_t)b * 589824 + (size_t)o * 2304 + n] = bfbits(acc[nt][r]);
      }
    __syncthreads();
  }
}

// ---------- K2: flash attention, split-KV (or DIRECT single-pass) ----------
// grid (18, 32, nc). Fixed-scale softmax p = exp2(s); partials combine by plain
// addition. K staged from head-major khm (contiguous 4KB tiles, 8 lines/load);
// source chunk pre-swizzled (c ^= (c>>2)&3) to match the LDS frag-read XOR.
template <bool DIRECT>
__global__ __launch_bounds__(256) void k_attn(const unsigned short* __restrict__ qhm,
                                              const unsigned short* __restrict__ khm,
                                              const unsigned short* __restrict__ vN,
                                              unsigned short* __restrict__ partO,
                                              float* __restrict__ partS,
                                              unsigned short* __restrict__ attT,
                                              int tpc) {
  __shared__ __align__(16) unsigned char sm[32768];  // [0,16K)=P (4K/wave), [16K,24K)=K dbuf, [24K,32K)=V dbuf
  const int l = threadIdx.x & 63, w = threadIdx.x >> 6;
  const int lr = l & 15, lg = l >> 4;
  const int bh = blockIdx.y, b = bh >> 3, h = bh & 7;
  const int i0 = blockIdx.x * 128 + w * 32;
  const int c = blockIdx.z, t0 = c * tpc;
  unsigned char* smw = sm + w * 4096;
  const size_t slab = (size_t)bh * 2304;

  bf16x8 qf[2];
  {
    const unsigned short* qbase = qhm + (slab + i0) * 32;
#pragma unroll
    for (int it = 0; it < 2; ++it)
      qf[it] = *(const bf16x8*)(qbase + (it * 16 + lr) * 32 + lg * 8);
  }

  bf16x8 ones;
#pragma unroll
  for (int e = 0; e < 8; ++e) ones[e] = (__bf16)1.0f;

  f32x4 oacc[2][2];
#pragma unroll
  for (int i = 0; i < 2; ++i)
#pragma unroll
    for (int j = 0; j < 2; ++j) oacc[i][j] = (f32x4){0.f, 0.f, 0.f, 0.f};
  f32x4 psum[2];
  psum[0] = (f32x4){0.f, 0.f, 0.f, 0.f};
  psum[1] = (f32x4){0.f, 0.f, 0.f, 0.f};

  const unsigned short* kbase = khm + slab * 32 + (size_t)(64 * w + (l ^ ((l >> 2) & 3))) * 8;
  const int vks = w >> 1;
  const int vlg = (w * 2 + (l >> 5)) & 3;
  const unsigned short* vsrc = vN + (size_t)(b * 256 + h * 32 + (l & 31)) * 2304 + vks * 32 + vlg * 8;
  const int kdst = 16384 + w * 1024;  // + buf*4096
  const int vdst = 24576 + w * 1024;
  const int kxor = ((lg ^ (lr & 3)) << 4);

  gload16(kbase + (size_t)t0 * 2048, sm + kdst);
  gload16(vsrc + t0 * 64, sm + vdst);
  __syncthreads();

  for (int tt = 0; tt < tpc; ++tt) {
    const int buf = tt & 1;
    if (tt < tpc - 1) {
      const int nbuf = (tt + 1) & 1;
      gload16(kbase + (size_t)(t0 + tt + 1) * 2048, sm + kdst + nbuf * 4096);
      gload16(vsrc + (t0 + tt + 1) * 64, sm + vdst + nbuf * 4096);
    }

    const unsigned char* kb = sm + 16384 + buf * 4096;
    const unsigned char* vb = sm + 24576 + buf * 4096;

    bf16x8 kf[4];
    {
      const unsigned char* kread = kb + lr * 64 + kxor;
#pragma unroll
      for (int jt = 0; jt < 4; ++jt)
        kf[jt] = *(const bf16x8*)(kread + jt * 1024);
    }

    f32x4 s[4][2];
    const f32x4 zf = (f32x4){0.f, 0.f, 0.f, 0.f};
#pragma unroll
    for (int jt = 0; jt < 4; ++jt)
#pragma unroll
      for (int it = 0; it < 2; ++it)
        s[jt][it] = __builtin_amdgcn_mfma_f32_16x16x32_bf16(kf[jt], qf[it], zf, 0, 0, 0);

#pragma unroll
    for (int it = 0; it < 2; ++it) {
      const int iloc = it * 16 + lr;
      const unsigned swz = (unsigned)((iloc & 7) << 4);
      unsigned char* prow = smw + iloc * 128;
#pragma unroll
      for (int jt = 0; jt < 4; ++jt) {
        const float p0 = EXP2(s[jt][it][0]);
        const float p1 = EXP2(s[jt][it][1]);
        const float p2 = EXP2(s[jt][it][2]);
        const float p3 = EXP2(s[jt][it][3]);
        const unsigned jb = (unsigned)(jt * 32 + lg * 8);
        uint2 u;
        u.x = packbf2(p0, p1);
        u.y = packbf2(p2, p3);
        *(uint2*)(prow + (jb ^ swz)) = u;
      }
    }

    bf16x8 vf[2][2], pf[2][2];
#pragma unroll
    for (int dt = 0; dt < 2; ++dt)
#pragma unroll
      for (int ks = 0; ks < 2; ++ks)
        vf[dt][ks] = *(const bf16x8*)(vb + ks * 2048 + lg * 512 + (dt * 16 + lr) * 16);
#pragma unroll
    for (int it = 0; it < 2; ++it) {
      const int iloc = it * 16 + lr;
      const unsigned swz = (unsigned)((iloc & 7) << 4);
#pragma unroll
      for (int ks = 0; ks < 2; ++ks)
        pf[it][ks] = *(const bf16x8*)(smw + iloc * 128 + ((unsigned)(ks * 64 + lg * 16) ^ swz));
    }
#pragma unroll
    for (int dt = 0; dt < 2; ++dt)
#pragma unroll
      for (int it = 0; it < 2; ++it) {
        oacc[dt][it] = __builtin_amdgcn_mfma_f32_16x16x32_bf16(vf[dt][0], pf[it][0], oacc[dt][it], 0, 0, 0);
        oacc[dt][it] = __builtin_amdgcn_mfma_f32_16x16x32_bf16(vf[dt][1], pf[it][1], oacc[dt][it], 0, 0, 0);
      }
#pragma unroll
    for (int it = 0; it < 2; ++it) {
      psum[it] = __builtin_amdgcn_mfma_f32_16x16x32_bf16(ones, pf[it][0], psum[it], 0, 0, 0);
      psum[it] = __builtin_amdgcn_mfma_f32_16x16x32_bf16(ones, pf[it][1], psum[it], 0, 0, 0);
    }
    __syncthreads();
  }

  if (DIRECT) {
#pragma unroll
    for (int it = 0; it < 2; ++it) {
      const float inv = 1.0f / psum[it][0];
      const int iloc = it * 16 + lr;
      unsigned char* orow = smw + iloc * 68;
#pragma unroll
      for (int dt = 0; dt < 2; ++dt) {
        const int d = dt * 16 + lg * 4;
        *(unsigned*)(orow + d * 2) = packbf2(oacc[dt][it][0] * inv, oacc[dt][it][1] * inv);
        *(unsigned*)(orow + d * 2 + 4) = packbf2(oacc[dt][it][2] * inv, oacc[dt][it][3] * inv);
      }
    }
    __syncthreads();
    unsigned* attu = (unsigned*)attT;
#pragma unroll
    for (int it2 = 0; it2 < 8; ++it2) {
      const int lin = it2 * 64 + l;
      const int row = lin >> 4, k = lin & 15;
      const unsigned u = *(const unsigned*)(smw + row * 68 + k * 4);
      attu[(size_t)(b * 2304 + i0 + row) * 128 + h * 16 + k] = u;
    }
  } else {
    const size_t pbase = ((size_t)(c * 32 + bh) * 2304 + i0) * 32;
#pragma unroll
    for (int it = 0; it < 2; ++it)
#pragma unroll
      for (int dt = 0; dt < 2; ++dt) {
        const size_t addr = pbase + (size_t)(it * 16 + lr) * 32 + dt * 16 + lg * 4;
        uint2 u;
        u.x = packbf2(oacc[dt][it][0], oacc[dt][it][1]);
        u.y = packbf2(oacc[dt][it][2], oacc[dt][it][3]);
        *(uint2*)(partO + addr) = u;
      }
    if (lg == 0) {
      const size_t sbase = (size_t)(c * 32 + bh) * 2304 + i0;
      partS[sbase + lr] = psum[0][0];
      partS[sbase + 16 + lr] = psum[1][0];
    }
  }
}

// ---------- K3: out = LN(Wo @ att + x) * gamma + beta ----------
// COMBINE=true: B-staging sums split-KV partials inline. COMBINE=false: from attT.
template <bool COMBINE>
__global__ __launch_bounds__(256) void k_out_ln(const unsigned short* __restrict__ Wo,
                                                const unsigned short* __restrict__ attT,
                                                const unsigned short* __restrict__ partO,
                                                const float* __restrict__ partS,
                                                int nc,
                                                const float* __restrict__ x,
                                                const float* __restrict__ gamma,
                                                const float* __restrict__ beta,
                                                float* __restrict__ out) {
  __shared__ __align__(16) unsigned char alds[8192];
  __shared__ float wsum[4][16], wsq[4][16], smean[16], srstd[16];
  const int l = threadIdx.x & 63, w = threadIdx.x >> 6;
  const int lr = l & 15, lg = l >> 4;
  const int b = blockIdx.x / 144;
  const int n0 = (blockIdx.x % 144) * 16;
  const int row0 = w * 64;
  const size_t bn0 = (size_t)b * 2304 + n0;

  if (COMBINE) {
    const int t = threadIdx.x;
    const int row = t >> 4;
    const int i = n0 + row;
    const int cj0 = (t & 15) * 2;
#pragma unroll
    for (int ii = 0; ii < 2; ++ii) {
      const int cj = cj0 + ii;
      const int h = cj >> 2;
      const int d0 = (cj & 3) * 8;
      const int bh8 = b * 8 + h;
      float ssum = 0.f;
      float a0 = 0.f, a1 = 0.f, a2 = 0.f, a3 = 0.f, a4 = 0.f, a5 = 0.f, a6 = 0.f, a7 = 0.f;
      for (int cz = 0; cz < nc; ++cz) {
        const size_t rbase = (size_t)(cz * 32 + bh8) * 2304 + i;
        ssum += partS[rbase];
        const uint4 v = *(const uint4*)(partO + rbase * 32 + d0);
        a0 += bflo(v.x); a1 += bfhi(v.x);
        a2 += bflo(v.y); a3 += bfhi(v.y);
        a4 += bflo(v.z); a5 += bfhi(v.z);
        a6 += bflo(v.w); a7 += bfhi(v.w);
      }
      const float inv = 1.0f / ssum;
      uint4 u;
      u.x = packbf2(a0 * inv, a1 * inv);
      u.y = packbf2(a2 * inv, a3 * inv);
      u.z = packbf2(a4 * inv, a5 * inv);
      u.w = packbf2(a6 * inv, a7 * inv);
      *(uint4*)(alds + row * 512 + ((cj * 16) ^ ((row & 7) << 4))) = u;
    }
  } else {
    const int t = threadIdx.x;
    const int row = t >> 4;
    const int cj0 = (t & 15) * 2;
#pragma unroll
    for (int ii = 0; ii < 2; ++ii) {
      const int cj = cj0 + ii;
      const uint4 v = *(const uint4*)(attT + (bn0 + row) * 256 + cj * 8);
      *(uint4*)(alds + row * 512 + ((cj * 16) ^ ((row & 7) << 4))) = v;
    }
  }
  __syncthreads();

  f32x4 acc[4];
#pragma unroll
  for (int i = 0; i < 4; ++i) acc[i] = (f32x4){0.f, 0.f, 0.f, 0.f};
  for (int ks = 0; ks < 8; ++ks) {
    const int c = ks * 32 + lg * 8;
    bf16x8 a[4], bb;
#pragma unroll
    for (int rt = 0; rt < 4; ++rt)
      a[rt] = *(const bf16x8*)(Wo + (size_t)(row0 + rt * 16 + lr) * 256 + c);
    bb = *(const bf16x8*)(alds + lr * 512 + (((unsigned)((ks * 4 + lg) * 16)) ^ ((lr & 7) << 4)));
#pragma unroll
    for (int rt = 0; rt < 4; ++rt)
      acc[rt] = __builtin_amdgcn_mfma_f32_16x16x32_bf16(a[rt], bb, acc[rt], 0, 0, 0);
  }
  const float* xb = x + (size_t)b * 589824;
  float vals[4][4];
  float s0 = 0.f, q0 = 0.f;
#pragma unroll
  for (int rt = 0; rt < 4; ++rt)
#pragma unroll
    for (int r = 0; r < 4; ++r) {
      const int o = row0 + rt * 16 + lg * 4 + r;
      const int n = n0 + lr;
      const float vv = acc[rt][r] + xb[(size_t)o * 2304 + n];
      vals[rt][r] = vv;
      s0 += vv;
      q0 += vv * vv;
    }
  s0 += __shfl_xor(s0, 16); s0 += __shfl_xor(s0, 32);
  q0 += __shfl_xor(q0, 16); q0 += __shfl_xor(q0, 32);
  if (l < 16) {
    wsum[w][l] = s0;
    wsq[w][l] = q0;
  }
  __syncthreads();
  if (threadIdx.x < 16) {
    const int c16 = threadIdx.x;
    const float S = wsum[0][c16] + wsum[1][c16] + wsum[2][c16] + wsum[3][c16];
    const float Q = wsq[0][c16] + wsq[1][c16] + wsq[2][c16] + wsq[3][c16];
    const float mean = S * (1.0f / 256.0f);
    const float var = Q * (1.0f / 256.0f) - mean * mean;
    smean[c16] = mean;
    srstd[c16] = rsqrtf(var + 1e-5f);
  }
  __syncthreads();
  {
    const float mean = smean[lr];
    const float rstd = srstd[lr];
    const int n = n0 + lr;
#pragma unroll
    for (int rt = 0; rt < 4; ++rt)
#pragma unroll
      for (int r = 0; r < 4; ++r) {
        const int o = row0 + rt * 16 + lg * 4 + r;
        out[(size_t)b * 589824 + (size_t)o * 2304 + n] =
            (vals[rt][r] - mean) * rstd * gamma[o] + beta[o];
      }
  }
}

extern "C" void kernel_launch(void* const* d_in, const int* in_sizes, int n_in,
                              void* d_out, int out_size, void* d_ws, size_t ws_size,
                              hipStream_t stream) {
  (void)in_sizes; (void)n_in; (void)out_size;
  const float* x = (const float*)d_in[0];
  const float* Wq = (const float*)d_in[1];
  const float* Wk = (const float*)d_in[2];
  const float* Wv = (const float*)d_in[3];
  const float* Wo = (const float*)d_in[4];
  const float* gamma = (const float*)d_in[5];
  const float* beta = (const float*)d_in[6];
  float* out = (float*)d_out;
  char* ws = (char*)d_ws;
  // ws layout (bytes):
  //   qhm 0..4.72M | khm 4.72..9.44M | vN 9.44..14.16M | WoB 14.16M (+128K) |
  //   pbase 14.29M: COMBINE -> partO[nc] + partS[nc]; DIRECT -> attT (4.72M).
  unsigned short* qhm = (unsigned short*)(ws);
  unsigned short* khm = (unsigned short*)(ws + 4718592);
  unsigned short* vN = (unsigned short*)(ws + 9437184);
  unsigned short* WoB = (unsigned short*)(ws + 14155776);
  const size_t pbase = 14286848;
  const size_t chunk = 4718592 + 294912;
  const size_t need4 = pbase + 4 * chunk;  // ~34.3 MB
  const size_t need2 = pbase + 2 * chunk;  // ~24.3 MB
  const int nc = (ws_size >= need4) ? 4 : (ws_size >= need2) ? 2 : 1;
  unsigned short* partO = (unsigned short*)(ws + pbase);
  float* partS = (float*)(ws + pbase + (size_t)nc * 4718592);
  unsigned short* attT = (unsigned short*)(ws + pbase);  // DIRECT path only

  k_qkv<<<dim3(160), 256, 0, stream>>>(x, Wq, Wk, Wv, Wo, qhm, khm, vN, WoB);
  if (nc > 1) {
    k_attn<false><<<dim3(18, 32, nc), 256, 0, stream>>>(qhm, khm, vN, partO, partS, attT, 36 / nc);
    k_out_ln<true><<<dim3(576), 256, 0, stream>>>(WoB, attT, partO, partS, nc, x, gamma, beta, out);
  } else {
    k_attn<true><<<dim3(18, 32, 1), 256, 0, stream>>>(qhm, khm, vN, attT, (float*)attT, attT, 36);
    k_out_ln<false><<<dim3(576), 256, 0, stream>>>(WoB, attT, partO, partS, 1, x, gamma, beta, out);
  }
}